// Round 1
// baseline (765.257 us; speedup 1.0000x reference)
//
#include <hip/hip_runtime.h>

#define L_SEQ 512
#define B_SZ  1024
#define HD    64

__device__ __forceinline__ float fast_sigmoid(float x) {
    // 1/(1+exp(-x)) via v_exp_f32 (2^x) + v_rcp_f32, ~1ulp each
    return __builtin_amdgcn_rcpf(1.0f + __builtin_amdgcn_exp2f(-1.4426950408889634f * x));
}
__device__ __forceinline__ float fast_tanh(float x) {
    // tanh(x) = 1 - 2/(exp(2x)+1); exp(2x) = 2^(x*2*log2(e))
    return 1.0f - 2.0f * __builtin_amdgcn_rcpf(1.0f + __builtin_amdgcn_exp2f(2.8853900817779268f * x));
}

#define FMA_Q(vq, warr, acc, i0) do {                      \
    acc = fmaf((vq).x, warr[(i0) + 0], acc);               \
    acc = fmaf((vq).y, warr[(i0) + 1], acc);               \
    acc = fmaf((vq).z, warr[(i0) + 2], acc);               \
    acc = fmaf((vq).w, warr[(i0) + 3], acc);               \
} while (0)

// 512 blocks x 256 threads; each block owns 2 batch rows and runs all 512 steps.
// Thread (j = tid&63, cw = tid>>6): output column j, k-chunk cw (16 k's of x-part
// and 16 k's of h-part). Weights held in VGPRs (96 f32/thread). xh broadcasts via
// wave-uniform LDS reads; partial dots reduced through LDS (lane-consecutive, no
// bank conflicts).
__global__ __launch_bounds__(256, 2) void gru_fused_kernel(
    const int* __restrict__ xind, const float* __restrict__ emb,
    const float* __restrict__ Wz, const float* __restrict__ Wr,
    const float* __restrict__ Wh, float* __restrict__ out)
{
    __shared__ float sm_xh[2][128];      // [row][ xt(0..63) | h(64..127) ]
    __shared__ float sm_rh[2][64];       // r * h
    __shared__ float sm_p1[2][2][4][64]; // [row][gate z/r][chunk][j]
    __shared__ float sm_p2[2][4][64];    // [row][chunk][j]

    const int j  = threadIdx.x & 63;
    const int cw = threadIdx.x >> 6;     // wave id == k-chunk
    const int kb = cw * 16;
    const int b0 = blockIdx.x * 2;

    // ---- weights into registers (coalesced: lane j consecutive) ----
    float wzx[16], wzh[16], wrx[16], wrh[16], whr[16], whx[16];
#pragma unroll
    for (int i = 0; i < 16; ++i) {
        wzx[i] = Wz[(kb + i) * 64 + j];        // z gate, xt part (rows 0..63)
        wzh[i] = Wz[(64 + kb + i) * 64 + j];   // z gate, h part  (rows 64..127)
        wrx[i] = Wr[(kb + i) * 64 + j];
        wrh[i] = Wr[(64 + kb + i) * 64 + j];
        whr[i] = Wh[(kb + i) * 64 + j];        // cand: rows 0..63 multiply r*h
        whx[i] = Wh[(64 + kb + i) * 64 + j];   // cand: rows 64..127 multiply xt
    }

    // ---- init: h = 0, load xt for t=0 ----
    if (cw < 2) {
        sm_xh[cw][64 + j] = 0.0f;
    } else {
        int r = cw - 2;
        int idx = xind[b0 + r];
        sm_xh[r][j] = emb[(size_t)idx * 64 + j];
    }
    __syncthreads();

    float accC[2];
    float z_reg = 0.0f, h_reg = 0.0f;

    for (int t = 0; t < L_SEQ; ++t) {
        // ---- prefetch next step's embedding row (waves 2,3), h-independent ----
        float ev = 0.0f;
        if (cw >= 2 && t < L_SEQ - 1) {
            int r = cw - 2;
            int idx = xind[(t + 1) * B_SZ + b0 + r];
            ev = emb[(size_t)idx * 64 + j];
        }

        // ---- Phase B: partial dots for z, r, and x-part of candidate ----
#pragma unroll
        for (int r = 0; r < 2; ++r) {
            const float4* px = (const float4*)(&sm_xh[r][kb]);       // uniform per wave
            const float4* ph = (const float4*)(&sm_xh[r][64 + kb]);  // uniform per wave
            float az = 0.0f, ar = 0.0f, ac = 0.0f;
#pragma unroll
            for (int q = 0; q < 4; ++q) {
                const int i0 = 4 * q;
                float4 xq = px[q];
                float4 hq = ph[q];
                FMA_Q(xq, wzx, az, i0);
                FMA_Q(xq, wrx, ar, i0);
                FMA_Q(xq, whx, ac, i0);
                FMA_Q(hq, wzh, az, i0);
                FMA_Q(hq, wrh, ar, i0);
            }
            sm_p1[r][0][cw][j] = az;
            sm_p1[r][1][cw][j] = ar;
            accC[r] = ac;
        }
        __syncthreads();

        // ---- Phase C: finish z (waves 0,1) / r and r*h (waves 2,3) ----
        {
            int r = cw & 1;
            if (cw < 2) {
                float s = sm_p1[r][0][0][j] + sm_p1[r][0][1][j]
                        + sm_p1[r][0][2][j] + sm_p1[r][0][3][j];
                z_reg = fast_sigmoid(s);
                h_reg = sm_xh[r][64 + j];
            } else {
                float s = sm_p1[r][1][0][j] + sm_p1[r][1][1][j]
                        + sm_p1[r][1][2][j] + sm_p1[r][1][3][j];
                float rr = fast_sigmoid(s);
                sm_rh[r][j] = rr * sm_xh[r][64 + j];
            }
        }
        __syncthreads();

        // ---- Phase D: candidate h-part partial dots ----
#pragma unroll
        for (int r = 0; r < 2; ++r) {
            const float4* pr = (const float4*)(&sm_rh[r][kb]);  // uniform per wave
            float a = accC[r];
#pragma unroll
            for (int q = 0; q < 4; ++q) {
                const int i0 = 4 * q;
                float4 rq = pr[q];
                FMA_Q(rq, whr, a, i0);
            }
            sm_p2[r][cw][j] = a;
        }
        __syncthreads();

        // ---- Phase E: finish candidate + blend (waves 0,1); commit prefetch (2,3) ----
        if (cw < 2) {
            int r = cw;
            float s = sm_p2[r][0][j] + sm_p2[r][1][j]
                    + sm_p2[r][2][j] + sm_p2[r][3][j];
            float hc = fast_tanh(s);
            float hn = fmaf(z_reg, hc - h_reg, h_reg);
            sm_xh[r][64 + j] = hn;
            out[(size_t)t * (B_SZ * HD) + (size_t)(b0 + r) * HD + j] = hn;
            if (t == L_SEQ - 1)
                out[(size_t)L_SEQ * B_SZ * HD + (size_t)(b0 + r) * HD + j] = hn;
        } else {
            int r = cw - 2;
            if (t < L_SEQ - 1)
                sm_xh[r][j] = ev;   // xt for step t+1 (xt of step t is dead after B)
        }
        __syncthreads();
    }
}

extern "C" void kernel_launch(void* const* d_in, const int* in_sizes, int n_in,
                              void* d_out, int out_size, void* d_ws, size_t ws_size,
                              hipStream_t stream) {
    (void)in_sizes; (void)n_in; (void)out_size; (void)d_ws; (void)ws_size;
    const int*   x   = (const int*)  d_in[0];
    const float* emb = (const float*)d_in[1];
    const float* Wz  = (const float*)d_in[2];
    const float* Wr  = (const float*)d_in[3];
    const float* Wh  = (const float*)d_in[4];
    float* out = (float*)d_out;

    gru_fused_kernel<<<dim3(B_SZ / 2), dim3(256), 0, stream>>>(x, emb, Wz, Wr, Wh, out);
}

// Round 2
// 763.162 us; speedup vs baseline: 1.0027x; 1.0027x over previous
//
#include <hip/hip_runtime.h>

#define L_SEQ 512
#define B_SZ  1024
#define HD    64

__device__ __forceinline__ float fast_sigmoid(float x) {
    return __builtin_amdgcn_rcpf(1.0f + __builtin_amdgcn_exp2f(-1.4426950408889634f * x));
}
__device__ __forceinline__ float fast_tanh(float x) {
    return 1.0f - 2.0f * __builtin_amdgcn_rcpf(1.0f + __builtin_amdgcn_exp2f(2.8853900817779268f * x));
}

#define FMA_Q(vq, warr, acc, i0) do {                      \
    acc = fmaf((vq).x, warr[(i0) + 0], acc);               \
    acc = fmaf((vq).y, warr[(i0) + 1], acc);               \
    acc = fmaf((vq).z, warr[(i0) + 2], acc);               \
    acc = fmaf((vq).w, warr[(i0) + 3], acc);               \
} while (0)

// Force a value to live in an arch VGPR and make its def opaque (not
// rematerializable / not sinkable into the loop). Zero instructions emitted.
#define PIN(x) asm volatile("" : "+v"(x))

// 512 blocks x 256 threads; each block owns 2 batch rows and runs all 512 steps.
// Thread (j = tid&63, cw = tid>>6): output column j, k-chunk cw. Weights held in
// VGPRs (96 f32/thread, pinned). xh broadcasts via wave-uniform LDS reads;
// partial dots reduced through LDS (lane-consecutive, no bank conflicts).
__global__ __launch_bounds__(256, 2) void gru_fused_kernel(
    const int* __restrict__ xind, const float* __restrict__ emb,
    const float* __restrict__ Wz, const float* __restrict__ Wr,
    const float* __restrict__ Wh, float* __restrict__ out)
{
    __shared__ float sm_xh[2][128];      // [row][ xt(0..63) | h(64..127) ]
    __shared__ float sm_rh[2][64];       // r * h
    __shared__ float sm_p1[2][2][4][64]; // [row][gate z/r][chunk][j]
    __shared__ float sm_p2[2][4][64];    // [row][chunk][j]

    const int j  = threadIdx.x & 63;
    const int cw = threadIdx.x >> 6;     // wave id == k-chunk
    const int kb = cw * 16;
    const int b0 = blockIdx.x * 2;

    // ---- weights into registers (coalesced: lane j consecutive) ----
    float wzx[16], wzh[16], wrx[16], wrh[16], whr[16], whx[16];
#pragma unroll
    for (int i = 0; i < 16; ++i) {
        wzx[i] = Wz[(kb + i) * 64 + j];        // z gate, xt part (rows 0..63)
        wzh[i] = Wz[(64 + kb + i) * 64 + j];   // z gate, h part  (rows 64..127)
        wrx[i] = Wr[(kb + i) * 64 + j];
        wrh[i] = Wr[(64 + kb + i) * 64 + j];
        whr[i] = Wh[(kb + i) * 64 + j];        // cand: rows 0..63 multiply r*h
        whx[i] = Wh[(64 + kb + i) * 64 + j];   // cand: rows 64..127 multiply xt
    }
#pragma unroll
    for (int i = 0; i < 16; ++i) {
        PIN(wzx[i]); PIN(wzh[i]); PIN(wrx[i]);
        PIN(wrh[i]); PIN(whr[i]); PIN(whx[i]);
    }

    // ---- init: h = 0, load xt for t=0 ----
    if (cw < 2) {
        sm_xh[cw][64 + j] = 0.0f;
    } else {
        int r = cw - 2;
        int idx = xind[b0 + r];
        sm_xh[r][j] = emb[(size_t)idx * 64 + j];
    }
    __syncthreads();

    float accC[2];
    float z_reg = 0.0f, h_reg = 0.0f;

    for (int t = 0; t < L_SEQ; ++t) {
        // ---- prefetch next step's embedding row (waves 2,3), h-independent ----
        float ev = 0.0f;
        if (cw >= 2 && t < L_SEQ - 1) {
            int r = cw - 2;
            int idx = xind[(t + 1) * B_SZ + b0 + r];
            ev = emb[(size_t)idx * 64 + j];
        }

        // ---- Phase B: partial dots for z, r, and x-part of candidate ----
#pragma unroll
        for (int r = 0; r < 2; ++r) {
            const float4* px = (const float4*)(&sm_xh[r][kb]);       // uniform per wave
            const float4* ph = (const float4*)(&sm_xh[r][64 + kb]);  // uniform per wave
            float az = 0.0f, ar = 0.0f, ac = 0.0f;
#pragma unroll
            for (int q = 0; q < 4; ++q) {
                const int i0 = 4 * q;
                float4 xq = px[q];
                float4 hq = ph[q];
                FMA_Q(xq, wzx, az, i0);
                FMA_Q(xq, wrx, ar, i0);
                FMA_Q(xq, whx, ac, i0);
                FMA_Q(hq, wzh, az, i0);
                FMA_Q(hq, wrh, ar, i0);
            }
            sm_p1[r][0][cw][j] = az;
            sm_p1[r][1][cw][j] = ar;
            accC[r] = ac;
        }
        __syncthreads();

        // ---- Phase C: finish z (waves 0,1) / r and r*h (waves 2,3) ----
        {
            int r = cw & 1;
            if (cw < 2) {
                float s = sm_p1[r][0][0][j] + sm_p1[r][0][1][j]
                        + sm_p1[r][0][2][j] + sm_p1[r][0][3][j];
                z_reg = fast_sigmoid(s);
                h_reg = sm_xh[r][64 + j];
            } else {
                float s = sm_p1[r][1][0][j] + sm_p1[r][1][1][j]
                        + sm_p1[r][1][2][j] + sm_p1[r][1][3][j];
                float rr = fast_sigmoid(s);
                sm_rh[r][j] = rr * sm_xh[r][64 + j];
            }
        }
        __syncthreads();

        // ---- Phase D: candidate h-part partial dots ----
#pragma unroll
        for (int r = 0; r < 2; ++r) {
            const float4* pr = (const float4*)(&sm_rh[r][kb]);  // uniform per wave
            float a = accC[r];
#pragma unroll
            for (int q = 0; q < 4; ++q) {
                const int i0 = 4 * q;
                float4 rq = pr[q];
                FMA_Q(rq, whr, a, i0);
            }
            sm_p2[r][cw][j] = a;
        }
        __syncthreads();

        // ---- Phase E: finish candidate + blend (waves 0,1); commit prefetch (2,3) ----
        if (cw < 2) {
            int r = cw;
            float s = sm_p2[r][0][j] + sm_p2[r][1][j]
                    + sm_p2[r][2][j] + sm_p2[r][3][j];
            float hc = fast_tanh(s);
            float hn = fmaf(z_reg, hc - h_reg, h_reg);
            sm_xh[r][64 + j] = hn;
            out[(size_t)t * (B_SZ * HD) + (size_t)(b0 + r) * HD + j] = hn;
            if (t == L_SEQ - 1)
                out[(size_t)L_SEQ * B_SZ * HD + (size_t)(b0 + r) * HD + j] = hn;
        } else {
            int r = cw - 2;
            if (t < L_SEQ - 1)
                sm_xh[r][j] = ev;   // xt for step t+1 (xt of step t is dead after B)
        }
        __syncthreads();
    }
}

extern "C" void kernel_launch(void* const* d_in, const int* in_sizes, int n_in,
                              void* d_out, int out_size, void* d_ws, size_t ws_size,
                              hipStream_t stream) {
    (void)in_sizes; (void)n_in; (void)out_size; (void)d_ws; (void)ws_size;
    const int*   x   = (const int*)  d_in[0];
    const float* emb = (const float*)d_in[1];
    const float* Wz  = (const float*)d_in[2];
    const float* Wr  = (const float*)d_in[3];
    const float* Wh  = (const float*)d_in[4];
    float* out = (float*)d_out;

    gru_fused_kernel<<<dim3(B_SZ / 2), dim3(256), 0, stream>>>(x, emb, Wz, Wr, Wh, out);
}